// Round 2
// baseline (18613.025 us; speedup 1.0000x reference)
//
#include <hip/hip_runtime.h>
#include <math.h>

#define NBLK   256
#define NTHR   512
#define TSTEPS 512
#define S      1024
#define B      64
#define O      128

// ws layout (floats):
//   th0 @ 0        [1024 s][64 b]
//   th1 @ 65536    [1024 s][64 b]
//   h   @ 131072   [1024 s][64 b]
//   sync@ 196608   ints: slots[256], gen
// Harness poisons ws with 0xAA -> as int32 that is negative, so
// "slot < k" / "gen < k" spin conditions are correct without any init kernel.

__device__ __forceinline__ int ld_acq(int* p) {
  return __hip_atomic_load(p, __ATOMIC_ACQUIRE, __HIP_MEMORY_SCOPE_AGENT);
}
__device__ __forceinline__ void st_rel(int* p, int v) {
  __hip_atomic_store(p, v, __ATOMIC_RELEASE, __HIP_MEMORY_SCOPE_AGENT);
}

__device__ __forceinline__ void redsr(float4& v) {
  v.x += __shfl_xor(v.x, 16); v.y += __shfl_xor(v.y, 16);
  v.z += __shfl_xor(v.z, 16); v.w += __shfl_xor(v.w, 16);
  v.x += __shfl_xor(v.x, 32); v.y += __shfl_xor(v.y, 32);
  v.z += __shfl_xor(v.z, 32); v.w += __shfl_xor(v.w, 32);
}

__global__ __launch_bounds__(NTHR) void ugrnn_persist(
    const float* __restrict__ x,
    const float* __restrict__ h_init,
    const float* __restrict__ w_o,
    const float* __restrict__ b_o,
    const float* __restrict__ w_u,
    const float* __restrict__ b_u,
    const float* __restrict__ w_r,
    const float* __restrict__ b_r,
    float* __restrict__ ws,
    float* __restrict__ out)
{
  // LDS: weights cached for the whole 512-step scan + reduction buffers
  __shared__ float w_lds[S * 8];     // [s][k], k = j*2+g (j=state col 0..3, g=0:u 1:r)  32KB
  __shared__ float wo_lds[S];        // w_o column                                        4KB
  __shared__ float red[8 * 9 * B];   // [wave][k(8 gate cols + o)][b]                    18KB
  __shared__ float tot[9 * B];       // summed over waves                               2.25KB

  const int tid  = threadIdx.x;
  const int blk  = blockIdx.x;
  const int c0   = blk * 4;          // this block's 4 state columns
  const int ocol = blk >> 1;         // shared output column (written by even blocks)

  float* th0 = ws;
  float* th1 = ws + 65536;
  float* h   = ws + 131072;
  int* slots = (int*)(ws + 196608);
  int* gen   = slots + NBLK;

  // ---- one-time: weights -> LDS ----
  for (int idx = tid; idx < S * 4; idx += NTHR) {
    int s = idx >> 2, j = idx & 3;
    w_lds[s * 8 + j * 2 + 0] = w_u[s * S + c0 + j];
    w_lds[s * 8 + j * 2 + 1] = w_r[s * S + c0 + j];
  }
  for (int s = tid; s < S; s += NTHR)
    wo_lds[s] = w_o[ocol * S + s];

  // ---- one-time: init h (transposed [s][b]) and th0 for our 4 cols ----
  if (tid < 256) {
    int j = tid >> 6, b = tid & 63;
    int s = c0 + j;
    float v = h_init[b * S + s];
    h[s * B + b]   = v;
    th0[s * B + b] = tanhf(v);
  }

  const int wav  = tid >> 6;     // 0..7: wave's K-slice [wav*128, wav*128+128)
  const int lane = tid & 63;
  const int sr   = lane >> 4;    // s-residue 0..3 within a 4-s chunk
  const int bq   = lane & 15;    // b-quad

  for (int t = 0; t <= TSTEPS; ++t) {
    // ---- grid barrier #(t+1): th_t from all blocks is visible after this ----
    {
      int k = t + 1;
      __syncthreads();
      if (blk == 0) {
        if (tid == 0) st_rel(&slots[0], k);
        if (tid > 0 && tid < NBLK) {
          while (ld_acq(&slots[tid]) < k) __builtin_amdgcn_s_sleep(1);
        }
        __syncthreads();
        if (tid == 0) st_rel(gen, k);
      } else {
        if (tid == 0) {
          st_rel(&slots[blk], k);
          while (ld_acq(gen) < k) __builtin_amdgcn_s_sleep(1);
        }
      }
      __syncthreads();
    }

    const float* thc = (t & 1) ? th1 : th0;
    float*       thn = (t & 1) ? th0 : th1;

    // ---- K-loop: 8 gate columns + 1 output column, K-slice of 128 s ----
    float4 acc0 = {0,0,0,0}, acc1 = {0,0,0,0}, acc2 = {0,0,0,0}, acc3 = {0,0,0,0};
    float4 acc4 = {0,0,0,0}, acc5 = {0,0,0,0}, acc6 = {0,0,0,0}, acc7 = {0,0,0,0};
    float4 acco = {0,0,0,0};

    const float* thp = thc + (wav * 128 + sr) * B + bq * 4;
    const float* wlp = &w_lds[(wav * 128 + sr) * 8];
    const float* wop = &wo_lds[wav * 128 + sr];

#define FMA4(A, W)                                                   \
    A.x = fmaf(th4.x, W, A.x); A.y = fmaf(th4.y, W, A.y);            \
    A.z = fmaf(th4.z, W, A.z); A.w = fmaf(th4.w, W, A.w);

    #pragma unroll 4
    for (int c = 0; c < 32; ++c) {
      float4 th4 = *(const float4*)thp;
      float4 w4a = *(const float4*)wlp;
      float4 w4b = *(const float4*)(wlp + 4);
      float  wos = *wop;
      FMA4(acc0, w4a.x) FMA4(acc1, w4a.y) FMA4(acc2, w4a.z) FMA4(acc3, w4a.w)
      FMA4(acc4, w4b.x) FMA4(acc5, w4b.y) FMA4(acc6, w4b.z) FMA4(acc7, w4b.w)
      FMA4(acco, wos)
      thp += 4 * B; wlp += 32; wop += 4;
    }
#undef FMA4

    // ---- reduce over the 4 s-residues (lanes 0..15 end up with full sums) ----
    redsr(acc0); redsr(acc1); redsr(acc2); redsr(acc3);
    redsr(acc4); redsr(acc5); redsr(acc6); redsr(acc7);
    redsr(acco);
    if (lane < 16) {
      *(float4*)&red[(wav * 9 + 0) * B + bq * 4] = acc0;
      *(float4*)&red[(wav * 9 + 1) * B + bq * 4] = acc1;
      *(float4*)&red[(wav * 9 + 2) * B + bq * 4] = acc2;
      *(float4*)&red[(wav * 9 + 3) * B + bq * 4] = acc3;
      *(float4*)&red[(wav * 9 + 4) * B + bq * 4] = acc4;
      *(float4*)&red[(wav * 9 + 5) * B + bq * 4] = acc5;
      *(float4*)&red[(wav * 9 + 6) * B + bq * 4] = acc6;
      *(float4*)&red[(wav * 9 + 7) * B + bq * 4] = acc7;
      *(float4*)&red[(wav * 9 + 8) * B + bq * 4] = acco;
    }
    __syncthreads();

    // ---- sum the 8 waves' partials ----
    {
      int k = tid >> 6, b = tid & 63;
      float sum = 0.f;
      #pragma unroll
      for (int w = 0; w < 8; ++w) sum += red[(w * 9 + k) * B + b];
      tot[k * B + b] = sum;
      if (tid < B) {
        float so = 0.f;
        #pragma unroll
        for (int w = 0; w < 8; ++w) so += red[(w * 9 + 8) * B + tid];
        tot[8 * B + tid] = so;
      }
    }
    __syncthreads();

    // ---- gate math + h/th update for our 4 cols ----
    if (tid < 256) {
      int j = tid >> 6, b = tid & 63;
      int s = c0 + j;
      float pu = tot[(j * 2 + 0) * B + b] + b_u[s];
      float pr = tot[(j * 2 + 1) * B + b] + b_r[s];
      float u  = 1.f / (1.f + expf(-pu));
      float r  = tanhf(pr);
      float hv = h[s * B + b];
      float hn = u * hv + (1.f - u) * r;
      h[s * B + b]   = hn;
      thn[s * B + b] = tanhf(hn);
    }

    // ---- err[t-1] = th_t @ w_o^T + b_o - x[t-1] (even block of each pair writes) ----
    if (tid < B && t >= 1 && !(blk & 1)) {
      size_t idx = (size_t)(t - 1) * (B * O) + (size_t)tid * O + ocol;
      out[idx] = tot[8 * B + tid] + b_o[ocol] - x[idx];
    }
  }
}

extern "C" void kernel_launch(void* const* d_in, const int* in_sizes, int n_in,
                              void* d_out, int out_size, void* d_ws, size_t ws_size,
                              hipStream_t stream)
{
  const float* x      = (const float*)d_in[0];
  const float* h_init = (const float*)d_in[1];
  const float* w_o    = (const float*)d_in[2];
  const float* b_o    = (const float*)d_in[3];
  const float* w_u    = (const float*)d_in[4];
  const float* b_u    = (const float*)d_in[5];
  const float* w_r    = (const float*)d_in[6];
  const float* b_r    = (const float*)d_in[7];
  float* out = (float*)d_out;
  float* ws  = (float*)d_ws;

  void* args[] = {
    (void*)&x, (void*)&h_init, (void*)&w_o, (void*)&b_o,
    (void*)&w_u, (void*)&b_u, (void*)&w_r, (void*)&b_r,
    (void*)&ws, (void*)&out
  };
  hipLaunchCooperativeKernel((const void*)ugrnn_persist,
                             dim3(NBLK), dim3(NTHR), args, 0, stream);
}

// Round 3
// 7131.409 us; speedup vs baseline: 2.6100x; 2.6100x over previous
//
#include <hip/hip_runtime.h>
#include <math.h>

#define NBLK   256
#define NTHR   512
#define TSTEPS 512

typedef float f32x4 __attribute__((ext_vector_type(4)));

// ws float layout:
//   th[g][par][1024 K][16 b] : g*32768 + par*16384, g in 0..3   (131072 floats)
//   slots[256] ints @ float-offset 131072 (poisoned 0xAA = negative, OK)
//
// LDS float layout (dynamic, 162,440 B):
//   w_lds [35][1024]  @ 0        (col-major: col*1024 + K; cols 0..31 gates(u,r interleaved),
//                                 32,33 = w_o cols, 34 = zero dummy)
//   red   [8][35][16] @ 35840
//   h_lds [256]       @ 40320    ([sl][b])
//   bu[16] @ 40576  br[16] @ 40592  bo[2] @ 40608
#define W_OFF   0
#define RED_OFF 35840
#define H_OFF   40320
#define BU_OFF  40576
#define BR_OFF  40592
#define BO_OFF  40608
#define SMEM_FLOATS 40612
#define SMEM_BYTES  (SMEM_FLOATS * 4)

#define LD8(a, p)                                                         \
  asm volatile(                                                           \
    "global_load_dwordx4 %0, %8, off sc0 sc1\n\t"                         \
    "global_load_dwordx4 %1, %8, off offset:256 sc0 sc1\n\t"              \
    "global_load_dwordx4 %2, %8, off offset:512 sc0 sc1\n\t"              \
    "global_load_dwordx4 %3, %8, off offset:768 sc0 sc1\n\t"              \
    "global_load_dwordx4 %4, %8, off offset:1024 sc0 sc1\n\t"             \
    "global_load_dwordx4 %5, %8, off offset:1280 sc0 sc1\n\t"             \
    "global_load_dwordx4 %6, %8, off offset:1536 sc0 sc1\n\t"             \
    "global_load_dwordx4 %7, %8, off offset:1792 sc0 sc1"                 \
    : "=&v"(a##0), "=&v"(a##1), "=&v"(a##2), "=&v"(a##3),                 \
      "=&v"(a##4), "=&v"(a##5), "=&v"(a##6), "=&v"(a##7)                  \
    : "v"(p) : "memory")

#define WAIT8(a)                                                          \
  asm volatile("s_waitcnt vmcnt(8)"                                       \
    : "+v"(a##0), "+v"(a##1), "+v"(a##2), "+v"(a##3),                     \
      "+v"(a##4), "+v"(a##5), "+v"(a##6), "+v"(a##7) :: "memory")

#define WAITL(a)                                                          \
  asm volatile("s_waitcnt vmcnt(0)"                                       \
    : "+v"(a##0), "+v"(a##1), "+v"(a##2), "+v"(a##3),                     \
      "+v"(a##4), "+v"(a##5), "+v"(a##6), "+v"(a##7) :: "memory")

#define FMA1(V, KI)                                                       \
  { const int kk = (KI);                                                  \
    _Pragma("unroll")                                                     \
    for (int j = 0; j < 9; ++j) {                                         \
      float wv = w_lds[wcol[j] + kk];                                     \
      acc[j].x = fmaf(V.x, wv, acc[j].x);                                 \
      acc[j].y = fmaf(V.y, wv, acc[j].y);                                 \
      acc[j].z = fmaf(V.z, wv, acc[j].z);                                 \
      acc[j].w = fmaf(V.w, wv, acc[j].w); } }

#define FMAB(a, KB)                                                       \
  FMA1(a##0, (KB)+0)  FMA1(a##1, (KB)+4)  FMA1(a##2, (KB)+8)              \
  FMA1(a##3, (KB)+12) FMA1(a##4, (KB)+16) FMA1(a##5, (KB)+20)             \
  FMA1(a##6, (KB)+24) FMA1(a##7, (KB)+28)

__device__ __forceinline__ void st1_mall(float* p, float v) {
  asm volatile("global_store_dword %0, %1, off sc0 sc1" :: "v"(p), "v"(v) : "memory");
}

__global__ __launch_bounds__(NTHR, 2) void ugrnn_persist(
    const float* __restrict__ x,
    const float* __restrict__ h_init,
    const float* __restrict__ w_o,
    const float* __restrict__ b_o,
    const float* __restrict__ w_u,
    const float* __restrict__ b_u,
    const float* __restrict__ w_r,
    const float* __restrict__ b_r,
    float* __restrict__ ws,
    float* __restrict__ out)
{
  extern __shared__ float smem[];
  float* w_lds = smem + W_OFF;
  float* red   = smem + RED_OFF;
  float* h_lds = smem + H_OFF;
  float* bu_l  = smem + BU_OFF;
  float* br_l  = smem + BR_OFF;
  float* bo_l  = smem + BO_OFF;

  const int tid = threadIdx.x;
  const int blk = blockIdx.x;
  const int g   = blk >> 6;        // batch group 0..3 (rows 16g..16g+15)
  const int c   = blk & 63;        // state-column block (cols 16c..16c+15)
  const int sg0 = c * 16;

  float* thb0 = ws + g * 32768;
  float* thb1 = thb0 + 16384;
  int* slots  = (int*)(ws + 131072);

  // ---------- one-time fills ----------
  // gate weights, col-major: col = sl*2 + (0:u,1:r)
  for (int idx = tid; idx < 16 * 1024; idx += NTHR) {
    int sl = idx & 15, K = idx >> 4;
    w_lds[(sl * 2 + 0) * 1024 + K] = w_u[K * 1024 + sg0 + sl];
    w_lds[(sl * 2 + 1) * 1024 + K] = w_r[K * 1024 + sg0 + sl];
  }
  // w_o cols (o = 2c, 2c+1)
  for (int idx = tid; idx < 2 * 1024; idx += NTHR) {
    int ci = idx >> 10, K = idx & 1023;
    w_lds[(32 + ci) * 1024 + K] = w_o[(2 * c + ci) * 1024 + K];
  }
  // dummy col 34 = 0
  for (int K = tid; K < 1024; K += NTHR) w_lds[34 * 1024 + K] = 0.f;
  if (tid < 16) { bu_l[tid] = b_u[sg0 + tid]; br_l[tid] = b_r[sg0 + tid]; }
  if (tid < 2)  { bo_l[tid] = b_o[2 * c + tid]; }

  // h slice + th_0
  if (tid < 256) {
    int sl = tid >> 4, b = tid & 15;
    float hv = h_init[(g * 16 + b) * 1024 + sg0 + sl];
    h_lds[tid] = hv;
    st1_mall(thb0 + (sg0 + sl) * 16 + b, tanhf(hv));
  }
  asm volatile("s_waitcnt vmcnt(0)" ::: "memory");
  __syncthreads();
  if (tid == 0)
    __hip_atomic_store(&slots[blk], 1, __ATOMIC_RELAXED, __HIP_MEMORY_SCOPE_AGENT);

  // ---------- per-lane constants ----------
  const int w_  = tid >> 6;            // wave 0..7, K-slice [128w, 128w+128)
  const int lane = tid & 63;
  const int bq  = lane & 3;            // b-quad
  const int cp  = (lane >> 2) & 3;     // col subset
  const int sr  = lane >> 4;           // K residue 0..3
  const int Kb0 = w_ * 128 + sr;

  int wcol[9];
  #pragma unroll
  for (int j = 0; j < 9; ++j) {
    int col = cp * 9 + j; if (col > 34) col = 34;
    wcol[j] = col * 1024;
  }

  // ---------- scan ----------
  for (int t = 0; t <= TSTEPS; ++t) {
    // wait for th_t from all blocks in group
    if (tid < 64) {
      int* sl = slots + g * 64 + tid;
      while (true) {
        int v = __hip_atomic_load(sl, __ATOMIC_RELAXED, __HIP_MEMORY_SCOPE_AGENT);
        if (__ballot(v >= t + 1) == ~0ull) break;
        __builtin_amdgcn_s_sleep(2);
      }
    }
    __syncthreads();

    const float* thc = (t & 1) ? thb1 : thb0;
    float*       thn = (t & 1) ? thb0 : thb1;

    f32x4 acc[9];
    #pragma unroll
    for (int j = 0; j < 9; ++j) acc[j] = (f32x4)0.f;

    const float* thp = thc + Kb0 * 16 + bq * 4;
    f32x4 X0,X1,X2,X3,X4,X5,X6,X7, Y0,Y1,Y2,Y3,Y4,Y5,Y6,Y7;
    f32x4 Z0,Z1,Z2,Z3,Z4,Z5,Z6,Z7, V0,V1,V2,V3,V4,V5,V6,V7;
    LD8(X, thp);
    LD8(Y, thp + 512);
    WAIT8(X);
    LD8(Z, thp + 1024);
    FMAB(X, Kb0);
    WAIT8(Y);
    LD8(V, thp + 1536);
    FMAB(Y, Kb0 + 32);
    WAIT8(Z);
    FMAB(Z, Kb0 + 64);
    WAITL(V);
    FMAB(V, Kb0 + 96);

    // reduce over sr (4-way butterfly over lane bits 4,5)
    #pragma unroll
    for (int j = 0; j < 9; ++j) {
      acc[j].x += __shfl_xor(acc[j].x, 16); acc[j].y += __shfl_xor(acc[j].y, 16);
      acc[j].z += __shfl_xor(acc[j].z, 16); acc[j].w += __shfl_xor(acc[j].w, 16);
      acc[j].x += __shfl_xor(acc[j].x, 32); acc[j].y += __shfl_xor(acc[j].y, 32);
      acc[j].z += __shfl_xor(acc[j].z, 32); acc[j].w += __shfl_xor(acc[j].w, 32);
    }
    if (lane < 16) {
      #pragma unroll
      for (int j = 0; j < 9; ++j) {
        int col = cp * 9 + j; if (col > 34) col = 34;
        *(f32x4*)&red[(w_ * 35 + col) * 16 + bq * 4] = acc[j];
      }
    }
    __syncthreads();

    // sum the 8 wave partials -> red row 0
    {
      int col = tid >> 4, b = tid & 15;
      float s = 0.f;
      #pragma unroll
      for (int w2 = 0; w2 < 8; ++w2) s += red[(w2 * 35 + col) * 16 + b];
      red[col * 16 + b] = s;
      if (tid < 32) {
        int col2 = 32 + (tid >> 4);
        float s2 = 0.f;
        #pragma unroll
        for (int w2 = 0; w2 < 8; ++w2) s2 += red[(w2 * 35 + col2) * 16 + b];
        red[col2 * 16 + b] = s2;
      }
    }
    __syncthreads();

    // gate math + h/th update
    if (tid < 256 && t < TSTEPS) {
      int sl = tid >> 4, b = tid & 15;
      float pu = red[(2 * sl) * 16 + b] + bu_l[sl];
      float pr = red[(2 * sl + 1) * 16 + b] + br_l[sl];
      float u  = 1.f / (1.f + expf(-pu));
      float rr = tanhf(pr);
      float hv = h_lds[tid];
      float hn = u * hv + (1.f - u) * rr;
      h_lds[tid] = hn;
      st1_mall(thn + (sg0 + sl) * 16 + b, tanhf(hn));
    }
    // err[t-1] = th_t @ w_o^T + b_o - x[t-1]
    if (tid >= 256 && tid < 288 && t >= 1) {
      int oi = (tid >> 4) & 1, b = tid & 15;
      size_t idx = (size_t)((t - 1) * 64 + g * 16 + b) * 128 + 2 * c + oi;
      out[idx] = red[(32 + oi) * 16 + b] + bo_l[oi] - x[idx];
    }

    asm volatile("s_waitcnt vmcnt(0)" ::: "memory");
    __syncthreads();
    if (tid == 0 && t < TSTEPS)
      __hip_atomic_store(&slots[blk], t + 2, __ATOMIC_RELAXED, __HIP_MEMORY_SCOPE_AGENT);
  }
}

extern "C" void kernel_launch(void* const* d_in, const int* in_sizes, int n_in,
                              void* d_out, int out_size, void* d_ws, size_t ws_size,
                              hipStream_t stream)
{
  const float* x      = (const float*)d_in[0];
  const float* h_init = (const float*)d_in[1];
  const float* w_o    = (const float*)d_in[2];
  const float* b_o    = (const float*)d_in[3];
  const float* w_u    = (const float*)d_in[4];
  const float* b_u    = (const float*)d_in[5];
  const float* w_r    = (const float*)d_in[6];
  const float* b_r    = (const float*)d_in[7];
  float* out = (float*)d_out;
  float* ws  = (float*)d_ws;

  hipFuncSetAttribute((const void*)ugrnn_persist,
                      hipFuncAttributeMaxDynamicSharedMemorySize, SMEM_BYTES);

  void* args[] = {
    (void*)&x, (void*)&h_init, (void*)&w_o, (void*)&b_o,
    (void*)&w_u, (void*)&b_u, (void*)&w_r, (void*)&b_r,
    (void*)&ws, (void*)&out
  };
  hipLaunchCooperativeKernel((const void*)ugrnn_persist,
                             dim3(NBLK), dim3(NTHR), args, SMEM_BYTES, stream);
}

// Round 9
// 3303.014 us; speedup vs baseline: 5.6352x; 2.1591x over previous
//
#include <hip/hip_runtime.h>
#include <math.h>

#define NBLK   256
#define NTHR   512
#define TSTEPS 512

typedef float        f32x4  __attribute__((ext_vector_type(4)));
typedef unsigned int u32x4  __attribute__((ext_vector_type(4)));
typedef short        bf16x8 __attribute__((ext_vector_type(8)));

union UAB { u32x4 u; bf16x8 s; };

// ---------------- ws (u32 units) ----------------
//   th_pair[g=4][buf=2][b=16][K=1024] u32  (hi bf16 in top 16, lo bf16 in low 16)
//   slots[256] ints @ 131072   (poisoned 0xAA.. = negative, OK for ">= t+1" waits)

// ---------------- LDS (float units) ----------------
// BF    [kc=32][T=2][hl=2][lane=64][4 u32]   @ 0       (131072 B)  MFMA B-fragments
// wo_l  [2][1024] f32                        @ 32768   (8 KB)
// redf  [8 waves][512] f32                   @ 34816   (16 KB)  C-tile partials
// po_f  [8 waves][32] f32                    @ 38912   (1 KB)   o-proj partials
// tot   [512] f32                            @ 39168
// totpo [32] f32                             @ 39680
// h_lds [256] f32                            @ 39712
// bu[16] @ 39968  br[16] @ 39984  bo[2] @ 40000
#define WO_F   32768
#define RED_F  34816
#define PO_F   38912
#define TOT_F  39168
#define TPO_F  39680
#define HL_F   39712
#define BU_F   39968
#define BR_F   39984
#define BO_F   40000
#define SMEM_FLOATS 40002
#define SMEM_BYTES  (SMEM_FLOATS * 4)

#define LDA(ua, ub, p)                                                    \
  asm volatile(                                                           \
    "global_load_dwordx4 %0, %2, off sc0 sc1\n\t"                         \
    "global_load_dwordx4 %1, %2, off offset:16 sc0 sc1"                   \
    : "=&v"(ua), "=&v"(ub) : "v"(p) : "memory")

__device__ __forceinline__ void stu_mall(unsigned int* p, unsigned int v) {
  asm volatile("global_store_dword %0, %1, off sc0 sc1" :: "v"(p), "v"(v) : "memory");
}

// One K=32 chunk: wait its A pair, unpack hi/lo frags, 6 MFMAs, o-proj VALU.
#define PROC_KC(KCL, VM, ua, ub)                                          \
  {                                                                       \
    asm volatile("s_waitcnt vmcnt(" #VM ")"                               \
                 : "+v"(ua), "+v"(ub) :: "memory");                       \
    const int kcg = w_ * 4 + KCL;                                         \
    UAB Ah, Al;                                                           \
    Ah.u[0] = (ua[1] & 0xffff0000u) | (ua[0] >> 16);                      \
    Ah.u[1] = (ua[3] & 0xffff0000u) | (ua[2] >> 16);                      \
    Ah.u[2] = (ub[1] & 0xffff0000u) | (ub[0] >> 16);                      \
    Ah.u[3] = (ub[3] & 0xffff0000u) | (ub[2] >> 16);                      \
    Al.u[0] = (ua[1] << 16) | (ua[0] & 0xffffu);                          \
    Al.u[1] = (ua[3] << 16) | (ua[2] & 0xffffu);                          \
    Al.u[2] = (ub[1] << 16) | (ub[0] & 0xffffu);                          \
    Al.u[3] = (ub[3] << 16) | (ub[2] & 0xffffu);                          \
    bf16x8 bUh = Bf[(kcg * 4 + 0) * 64 + lane];                           \
    bf16x8 bUl = Bf[(kcg * 4 + 1) * 64 + lane];                           \
    bf16x8 bRh = Bf[(kcg * 4 + 2) * 64 + lane];                           \
    bf16x8 bRl = Bf[(kcg * 4 + 3) * 64 + lane];                           \
    accU = __builtin_amdgcn_mfma_f32_16x16x32_bf16(Ah.s, bUh, accU,0,0,0);\
    accU = __builtin_amdgcn_mfma_f32_16x16x32_bf16(Ah.s, bUl, accU,0,0,0);\
    accU = __builtin_amdgcn_mfma_f32_16x16x32_bf16(Al.s, bUh, accU,0,0,0);\
    accR = __builtin_amdgcn_mfma_f32_16x16x32_bf16(Ah.s, bRh, accR,0,0,0);\
    accR = __builtin_amdgcn_mfma_f32_16x16x32_bf16(Ah.s, bRl, accR,0,0,0);\
    accR = __builtin_amdgcn_mfma_f32_16x16x32_bf16(Al.s, bRh, accR,0,0,0);\
    _Pragma("unroll")                                                     \
    for (int j = 0; j < 8; ++j) {                                         \
      unsigned int uw = (j < 4) ? ua[j] : ub[j - 4];                      \
      float tf = __uint_as_float(uw & 0xffff0000u)                        \
               + __uint_as_float(uw << 16);                               \
      int kidx = kcg * 32 + kb8 + j;                                      \
      po0 = fmaf(wo_l[kidx], tf, po0);                                    \
      po1 = fmaf(wo_l[1024 + kidx], tf, po1);                             \
    }                                                                     \
  }

__global__ __launch_bounds__(NTHR) void ugrnn_persist(
    const float* __restrict__ x,
    const float* __restrict__ h_init,
    const float* __restrict__ w_o,
    const float* __restrict__ b_o,
    const float* __restrict__ w_u,
    const float* __restrict__ b_u,
    const float* __restrict__ w_r,
    const float* __restrict__ b_r,
    float* __restrict__ ws,
    float* __restrict__ out)
{
  extern __shared__ float smem[];
  unsigned int* BFu  = (unsigned int*)smem;
  const bf16x8* Bf   = (const bf16x8*)smem;
  float* wo_l  = smem + WO_F;
  float* redf  = smem + RED_F;
  float* po_f  = smem + PO_F;
  float* tot   = smem + TOT_F;
  float* totpo = smem + TPO_F;
  float* h_lds = smem + HL_F;
  float* bu_l  = smem + BU_F;
  float* br_l  = smem + BR_F;
  float* bo_l  = smem + BO_F;

  const int tid = threadIdx.x;
  const int blk = blockIdx.x;
  const int g   = blk >> 6;        // batch group: rows 16g .. 16g+15
  const int cb  = blk & 63;        // state-column block: cols 16cb .. 16cb+15
  const int sg0 = cb * 16;

  unsigned int* thp_base = (unsigned int*)ws;         // th_pair buffers
  int* slots = (int*)(thp_base + 131072);

  // ---------------- one-time setup ----------------
  // MFMA B-fragments for w_u/w_r hi+lo.  Frag: lane l -> n=l&15, k=(l>>4)*8+j.
  // 16384 items = kc(32) x T(2) x lane(64) x r(4); each writes hi and lo word.
  for (int widx = tid; widx < 16384; widx += NTHR) {
    int r  = widx & 3;
    int l  = (widx >> 2) & 63;
    int T  = (widx >> 8) & 1;
    int kc = widx >> 9;
    int n  = l & 15, kb = l >> 4;
    int Ka = kc * 32 + kb * 8 + 2 * r;
    const float* Wsrc = T ? w_r : w_u;
    float wa = Wsrc[(size_t)Ka * 1024 + sg0 + n];
    float wb = Wsrc[(size_t)(Ka + 1) * 1024 + sg0 + n];
    unsigned int ha = __float_as_uint(wa) & 0xffff0000u;
    unsigned int hb = __float_as_uint(wb) & 0xffff0000u;
    unsigned int la = __float_as_uint(wa - __uint_as_float(ha)) >> 16;
    unsigned int lb = __float_as_uint(wb - __uint_as_float(hb)) >> 16;
    unsigned int base = kc * 1024 + T * 512 + l * 4 + r;
    BFu[base]       = hb | (ha >> 16);      // hi frag word (j=2r+1 high, j=2r low)
    BFu[base + 256] = (lb << 16) | la;      // lo frag word
  }
  for (int idx = tid; idx < 2048; idx += NTHR) {
    int o = idx >> 10, K = idx & 1023;
    wo_l[idx] = w_o[(size_t)(2 * cb + o) * 1024 + K];
  }
  if (tid < 16) { bu_l[tid] = b_u[sg0 + tid]; br_l[tid] = b_r[sg0 + tid]; }
  if (tid < 2)  { bo_l[tid] = b_o[2 * cb + tid]; }

  // h + th0 (packed hi|lo) ; th_pair[g][buf][b][K]
  if (tid < 256) {
    int b = tid >> 4, sl = tid & 15;
    float hv = h_init[(size_t)(g * 16 + b) * 1024 + sg0 + sl];
    h_lds[tid] = hv;
    float th = tanhf(hv);
    unsigned int hbits = __float_as_uint(th) & 0xffff0000u;
    float lof = th - __uint_as_float(hbits);
    unsigned int pk = hbits | (__float_as_uint(lof) >> 16);
    stu_mall(thp_base + (size_t)(g * 2 + 0) * 16384 + b * 1024 + sg0 + sl, pk);
  }
  asm volatile("s_waitcnt vmcnt(0)" ::: "memory");
  __syncthreads();
  if (tid == 0)
    __hip_atomic_store(&slots[blk], 1, __ATOMIC_RELAXED, __HIP_MEMORY_SCOPE_AGENT);

  // ---------------- per-lane constants ----------------
  const int w_   = tid >> 6;          // wave 0..7 -> K-slice [128w, 128w+128)
  const int lane = tid & 63;
  const int kb8  = (lane >> 4) * 8;   // k sub-offset within K=32 chunk

  // ---------------- scan ----------------
  for (int t = 0; t <= TSTEPS; ++t) {
    // wait for th_t from all 64 blocks of this group
    if (tid < 64) {
      int* sl = slots + g * 64 + tid;
      while (true) {
        int v = __hip_atomic_load(sl, __ATOMIC_RELAXED, __HIP_MEMORY_SCOPE_AGENT);
        if (__ballot(v >= t + 1) == ~0ull) break;
        __builtin_amdgcn_s_sleep(1);
      }
    }
    __syncthreads();

    const unsigned int* thc = thp_base + (size_t)(g * 2 + (t & 1)) * 16384;

    // prefetch x for the (t-1) error output (used after the flag store)
    float xv = 0.f; int oi = 0, bb = 0; size_t xidx = 0;
    if (tid >= 256 && tid < 288) {
      oi = (tid >> 4) & 1; bb = tid & 15;
      int te = (t >= 1) ? t - 1 : 0;
      xidx = ((size_t)(te * 64 + g * 16 + bb)) * 128 + 2 * cb + oi;
      asm volatile("global_load_dword %0, %1, off"
                   : "=v"(xv) : "v"(x + xidx) : "memory");
    }

    // issue all A-fragment loads (th_t, packed hi|lo), 2 dwordx4 per K=32 chunk
    const unsigned int* ap = thc + (lane & 15) * 1024 + w_ * 128 + kb8;
    u32x4 a0a, a0b, a1a, a1b, a2a, a2b, a3a, a3b;
    LDA(a0a, a0b, ap);
    LDA(a1a, a1b, ap + 32);
    LDA(a2a, a2b, ap + 64);
    LDA(a3a, a3b, ap + 96);

    f32x4 accU = {0.f, 0.f, 0.f, 0.f};
    f32x4 accR = {0.f, 0.f, 0.f, 0.f};
    float po0 = 0.f, po1 = 0.f;

    PROC_KC(0, 6, a0a, a0b)
    PROC_KC(1, 4, a1a, a1b)
    PROC_KC(2, 2, a2a, a2b)
    PROC_KC(3, 0, a3a, a3b)

    // o-proj: reduce over kb (lane bits 4,5)
    po0 += __shfl_xor(po0, 16); po0 += __shfl_xor(po0, 32);
    po1 += __shfl_xor(po1, 16); po1 += __shfl_xor(po1, 32);

    // stash per-wave partials
    *(f32x4*)(redf + w_ * 512 +       lane * 4) = accU;
    *(f32x4*)(redf + w_ * 512 + 256 + lane * 4) = accR;
    if (lane < 16) {
      po_f[w_ * 32 +      lane] = po0;
      po_f[w_ * 32 + 16 + lane] = po1;
    }
    __syncthreads();

    // cross-wave sums
    {
      float s = 0.f;
      #pragma unroll
      for (int w2 = 0; w2 < 8; ++w2) s += redf[w2 * 512 + tid];
      tot[tid] = s;
      if (tid < 32) {
        float sp = 0.f;
        #pragma unroll
        for (int w2 = 0; w2 < 8; ++w2) sp += po_f[w2 * 32 + tid];
        totpo[tid] = sp;
      }
    }
    __syncthreads();

    // gate math + h/th update (C frag: idx = ((m>>2)*16+n)*4 + (m&3), m=b, n=sl)
    if (tid < 256 && t < TSTEPS) {
      int b = tid >> 4, sl = tid & 15;
      int ci = ((b >> 2) * 16 + sl) * 4 + (b & 3);
      float pu = tot[ci]       + bu_l[sl];
      float pr = tot[256 + ci] + br_l[sl];
      float u  = 1.f / (1.f + expf(-pu));
      float rr = tanhf(pr);
      float hv = h_lds[tid];
      float hn = u * hv + (1.f - u) * rr;
      h_lds[tid] = hn;
      float th = tanhf(hn);
      unsigned int hbits = __float_as_uint(th) & 0xffff0000u;
      float lof = th - __uint_as_float(hbits);
      unsigned int pk = hbits | (__float_as_uint(lof) >> 16);
      unsigned int* thn = thp_base + (size_t)(g * 2 + ((t + 1) & 1)) * 16384;
      stu_mall(thn + b * 1024 + sg0 + sl, pk);
    }

    // drain th stores (and xv), then post flag
    asm volatile("s_waitcnt vmcnt(0)" : "+v"(xv) :: "memory");
    __syncthreads();
    if (tid == 0 && t < TSTEPS)
      __hip_atomic_store(&slots[blk], t + 2, __ATOMIC_RELAXED, __HIP_MEMORY_SCOPE_AGENT);

    // error output for step t-1 (off the critical path; overlaps next poll)
    if (tid >= 256 && tid < 288 && t >= 1)
      out[xidx] = totpo[oi * 16 + bb] + bo_l[oi] - xv;
  }
}

extern "C" void kernel_launch(void* const* d_in, const int* in_sizes, int n_in,
                              void* d_out, int out_size, void* d_ws, size_t ws_size,
                              hipStream_t stream)
{
  const float* x      = (const float*)d_in[0];
  const float* h_init = (const float*)d_in[1];
  const float* w_o    = (const float*)d_in[2];
  const float* b_o    = (const float*)d_in[3];
  const float* w_u    = (const float*)d_in[4];
  const float* b_u    = (const float*)d_in[5];
  const float* w_r    = (const float*)d_in[6];
  const float* b_r    = (const float*)d_in[7];
  float* out = (float*)d_out;
  float* ws  = (float*)d_ws;

  hipFuncSetAttribute((const void*)ugrnn_persist,
                      hipFuncAttributeMaxDynamicSharedMemorySize, SMEM_BYTES);

  void* args[] = {
    (void*)&x, (void*)&h_init, (void*)&w_o, (void*)&b_o,
    (void*)&w_u, (void*)&b_u, (void*)&w_r, (void*)&b_r,
    (void*)&ws, (void*)&out
  };
  hipLaunchCooperativeKernel((const void*)ugrnn_persist,
                             dim3(NBLK), dim3(NTHR), args, SMEM_BYTES, stream);
}